// Round 6
// baseline (42.489 us; speedup 1.0000x reference)
//
#include <hip/hip_runtime.h>
#include <hip/hip_bf16.h>

// Quantum layer: 4 qubits, 2 layers. Everything after the RY(x) encoding is a
// fixed unitary U (weights are batch-constant). Each output q is multilinear
// in (1, cos th_p, sin th_p) per qubit: 81 coefficients per output.
// qsetup (4 blocks) computes C[4][84] (81 + 3 pad) from weights into d_ws.
// qmain: coefficients pulled into SGPRs via explicit s_load_dwordx16 inline
// asm (per-wave scalar path, no per-lane VMEM), register-lean nested Horner.
// Round-5 crash root-cause: "=s" outputs could alias the pointer input %6;
// loads 2..6 then used a clobbered base. Fixed with early-clobber "=&s".

typedef float f32x16 __attribute__((ext_vector_type(16)));
typedef float f32x4  __attribute__((ext_vector_type(4)));

__global__ __launch_bounds__(256) void qsetup(const float* __restrict__ w,
                                              float* __restrict__ C) {
    __shared__ float Ur[16][16];   // [row k][col j]
    __shared__ float Ui[16][16];
    __shared__ float M[16][16];
    const int q = blockIdx.x;      // output qubit 0..3
    const int tid = threadIdx.x;

    // ---- step 1: threads 0..15 each simulate one basis column of U ----
    if (tid < 16) {
        float re[16], im[16];
#pragma unroll
        for (int i = 0; i < 16; ++i) { re[i] = (i == tid) ? 1.0f : 0.0f; im[i] = 0.0f; }

#pragma unroll
        for (int ly = 0; ly < 2; ++ly) {
#pragma unroll
            for (int qq = 0; qq < 4; ++qq) {
                const int mm = 8 >> qq;
                float th, c, s;
                // RX(w[ly][qq][0])
                th = w[(ly * 4 + qq) * 3 + 0] * 0.5f; c = __cosf(th); s = __sinf(th);
#pragma unroll
                for (int i = 0; i < 16; ++i) if (!(i & mm)) {
                    const int j = i | mm;
                    float r0 = re[i], i0 = im[i], r1 = re[j], i1 = im[j];
                    re[i] = c * r0 + s * i1;  im[i] = c * i0 - s * r1;
                    re[j] = s * i0 + c * r1;  im[j] = -s * r0 + c * i1;
                }
                // RY(w[ly][qq][1])
                th = w[(ly * 4 + qq) * 3 + 1] * 0.5f; c = __cosf(th); s = __sinf(th);
#pragma unroll
                for (int i = 0; i < 16; ++i) if (!(i & mm)) {
                    const int j = i | mm;
                    float r0 = re[i], i0 = im[i], r1 = re[j], i1 = im[j];
                    re[i] = c * r0 - s * r1;  im[i] = c * i0 - s * i1;
                    re[j] = s * r0 + c * r1;  im[j] = s * i0 + c * i1;
                }
                // RZ(w[ly][qq][2])
                th = w[(ly * 4 + qq) * 3 + 2] * 0.5f; c = __cosf(th); s = __sinf(th);
#pragma unroll
                for (int i = 0; i < 16; ++i) if (!(i & mm)) {
                    const int j = i | mm;
                    float r0 = re[i], i0 = im[i], r1 = re[j], i1 = im[j];
                    re[i] = c * r0 + s * i0;  im[i] = c * i0 - s * r0;
                    re[j] = c * r1 - s * i1;  im[j] = c * i1 + s * r1;
                }
            }
            // CNOT chain (q,q+1)
#pragma unroll
            for (int qq = 0; qq < 3; ++qq) {
                const int mc = 8 >> qq, mt = 8 >> (qq + 1);
#pragma unroll
                for (int i = 0; i < 16; ++i) if ((i & mc) && !(i & mt)) {
                    const int j = i | mt;
                    float tr = re[i]; re[i] = re[j]; re[j] = tr;
                    float ti = im[i]; im[i] = im[j]; im[j] = ti;
                }
            }
        }
#pragma unroll
        for (int k = 0; k < 16; ++k) { Ur[k][tid] = re[k]; Ui[k][tid] = im[k]; }
    }
    __syncthreads();

    // ---- step 2: M[j][l] = sum_k sign_q(k) Re(U[k,j] conj(U[k,l])) ----
    {
        const int j = tid >> 4, l = tid & 15;
        float acc = 0.0f;
#pragma unroll
        for (int k = 0; k < 16; ++k) {
            const float sgn = ((k >> (3 - q)) & 1) ? -1.0f : 1.0f;
            acc += sgn * (Ur[k][j] * Ur[k][l] + Ui[k][j] * Ui[k][l]);
        }
        M[j][l] = acc;
    }
    __syncthreads();

    // ---- step 3: project onto (1,cos,sin)^{(x)4} basis: 81 coeffs ----
    if (tid < 84) {
        if (tid < 81) {
            int ap[4];
            ap[0] = tid / 27; ap[1] = (tid / 9) % 3; ap[2] = (tid / 3) % 3; ap[3] = tid % 3;
            float acc = 0.0f;
            for (int m = 0; m < 16; ++m) {
                int j = 0, l = 0; float sgn = 1.0f;
#pragma unroll
                for (int p = 0; p < 4; ++p) {
                    const int o = (m >> (3 - p)) & 1;
                    int jb = o, lb = (ap[p] == 2) ? (o ^ 1) : o;
                    if (ap[p] == 1 && o) sgn = -sgn;
                    j = (j << 1) | jb; l = (l << 1) | lb;
                }
                acc += sgn * M[j][l];
            }
            C[q * 84 + tid] = acc * 0.0625f;
        } else {
            C[q * 84 + tid] = 0.0f;   // pad
        }
    }
}

__global__ __launch_bounds__(256) void qmain(const float* __restrict__ x,
                                             const float* __restrict__ C,
                                             float* __restrict__ out, int B) {
    const int b = blockIdx.x * 256 + threadIdx.x;
    if (b >= B) return;

    const float4 xv = *reinterpret_cast<const float4*>(x + (size_t)b * 8);
    float c0, s0, c1, s1, c2, s2, c3, s3;
    {
        float xs[4] = {xv.x, xv.y, xv.z, xv.w};
        float cc[4], ss[4];
#pragma unroll
        for (int q = 0; q < 4; ++q) {
            const float e = __expf(2.0f * xs[q]);
            const float t = 1.0f - __fdividef(2.0f, e + 1.0f);   // tanh(x)
            __sincosf(3.1415f * t, &ss[q], &cc[q]);
        }
        c0 = cc[0]; s0 = ss[0]; c1 = cc[1]; s1 = ss[1];
        c2 = cc[2]; s2 = ss[2]; c3 = cc[3]; s3 = ss[3];
    }

    // One output's 81 coefficients pulled into SGPRs via scalar loads (the
    // address is wave-uniform). All consumers data-depend on the asm outputs
    // and the waitcnt sits inside the same asm block (rule-#18 safe).
    // "=&s" early-clobber: outputs must NOT alias the pointer input %6.
    auto evalq = [&](const float* cq) -> float {
        f32x16 sA, sB, sCv, sD, sE; f32x4 sF;
        asm volatile(
            "s_load_dwordx16 %0, %6, 0x0\n\t"
            "s_load_dwordx16 %1, %6, 0x40\n\t"
            "s_load_dwordx16 %2, %6, 0x80\n\t"
            "s_load_dwordx16 %3, %6, 0xc0\n\t"
            "s_load_dwordx16 %4, %6, 0x100\n\t"
            "s_load_dwordx4  %5, %6, 0x140\n\t"
            "s_waitcnt lgkmcnt(0)"
            : "=&s"(sA), "=&s"(sB), "=&s"(sCv), "=&s"(sD), "=&s"(sE), "=&s"(sF)
            : "s"(cq));
#define CQ(e) ((e) < 16 ? sA[(e)] : (e) < 32 ? sB[(e) - 16] : (e) < 48 ? sCv[(e) - 32] \
               : (e) < 64 ? sD[(e) - 48] : (e) < 80 ? sE[(e) - 64] : sF[(e) - 80])
        float acc = 0.0f;
#pragma unroll
        for (int i = 0; i < 3; ++i) {
            float ai = 0.0f;
#pragma unroll
            for (int j = 0; j < 3; ++j) {
                float aj = 0.0f;
#pragma unroll
                for (int k = 0; k < 3; ++k) {
                    const int base = ((i * 3 + j) * 3 + k) * 3;
                    const float t = __fmaf_rn(CQ(base + 2), s3,
                                    __fmaf_rn(CQ(base + 1), c3, CQ(base + 0)));
                    if (k == 0)      aj = t;
                    else if (k == 1) aj = __fmaf_rn(t, c2, aj);
                    else             aj = __fmaf_rn(t, s2, aj);
                }
                if (j == 0)      ai = aj;
                else if (j == 1) ai = __fmaf_rn(aj, c1, ai);
                else             ai = __fmaf_rn(aj, s1, ai);
            }
            if (i == 0)      acc = ai;
            else if (i == 1) acc = __fmaf_rn(ai, c0, acc);
            else             acc = __fmaf_rn(ai, s0, acc);
        }
#undef CQ
        return acc;
    };

    float4 evv;
    evv.x = evalq(C + 0 * 84);
    evv.y = evalq(C + 1 * 84);
    evv.z = evalq(C + 2 * 84);
    evv.w = evalq(C + 3 * 84);

    *reinterpret_cast<float4*>(out + (size_t)b * 4) = evv;
}

extern "C" void kernel_launch(void* const* d_in, const int* in_sizes, int n_in,
                              void* d_out, int out_size, void* d_ws, size_t ws_size,
                              hipStream_t stream) {
    const float* x = (const float*)d_in[0];       // (B, 8) f32
    const float* w = (const float*)d_in[1];       // (2, 4, 3) f32
    float* out = (float*)d_out;                   // (B, 4) f32
    float* C = (float*)d_ws;                      // 4*84 floats scratch

    const int B = in_sizes[0] / 8;

    qsetup<<<4, 256, 0, stream>>>(w, C);
    qmain<<<(B + 255) / 256, 256, 0, stream>>>(x, C, out, B);
}

// Round 7
// 39.426 us; speedup vs baseline: 1.0777x; 1.0777x over previous
//
#include <hip/hip_runtime.h>
#include <hip/hip_bf16.h>

// Quantum layer: 4 qubits, 2 layers. Everything after the RY(x) encoding is a
// fixed unitary U (weights are batch-constant). Each output q is multilinear
// in (1, cos th_p, sin th_p) per qubit: 81 coefficients per output.
// qsetup (4 blocks) computes C as [4][27] float4 (triple + pad) into d_ws.
// qmain: EPT=2 elements interleaved at the innermost FMA; each coefficient
// triple is one global_load_dwordx4 (L1 broadcast), register-lean Horner.
// History: per-lane dword loads ~20us (R1/R4); LDS@184VGPR 52us (R3);
// SALU s_load path 42us (R6). This cuts VMEM instrs ~6x vs R4.

__global__ __launch_bounds__(256) void qsetup(const float* __restrict__ w,
                                              float* __restrict__ C) {
    __shared__ float Ur[16][16];   // [row k][col j]
    __shared__ float Ui[16][16];
    __shared__ float M[16][16];
    const int q = blockIdx.x;      // output qubit 0..3
    const int tid = threadIdx.x;

    // ---- step 1: threads 0..15 each simulate one basis column of U ----
    if (tid < 16) {
        float re[16], im[16];
#pragma unroll
        for (int i = 0; i < 16; ++i) { re[i] = (i == tid) ? 1.0f : 0.0f; im[i] = 0.0f; }

#pragma unroll
        for (int ly = 0; ly < 2; ++ly) {
#pragma unroll
            for (int qq = 0; qq < 4; ++qq) {
                const int mm = 8 >> qq;
                float th, c, s;
                // RX(w[ly][qq][0])
                th = w[(ly * 4 + qq) * 3 + 0] * 0.5f; c = __cosf(th); s = __sinf(th);
#pragma unroll
                for (int i = 0; i < 16; ++i) if (!(i & mm)) {
                    const int j = i | mm;
                    float r0 = re[i], i0 = im[i], r1 = re[j], i1 = im[j];
                    re[i] = c * r0 + s * i1;  im[i] = c * i0 - s * r1;
                    re[j] = s * i0 + c * r1;  im[j] = -s * r0 + c * i1;
                }
                // RY(w[ly][qq][1])
                th = w[(ly * 4 + qq) * 3 + 1] * 0.5f; c = __cosf(th); s = __sinf(th);
#pragma unroll
                for (int i = 0; i < 16; ++i) if (!(i & mm)) {
                    const int j = i | mm;
                    float r0 = re[i], i0 = im[i], r1 = re[j], i1 = im[j];
                    re[i] = c * r0 - s * r1;  im[i] = c * i0 - s * i1;
                    re[j] = s * r0 + c * r1;  im[j] = s * i0 + c * i1;
                }
                // RZ(w[ly][qq][2])
                th = w[(ly * 4 + qq) * 3 + 2] * 0.5f; c = __cosf(th); s = __sinf(th);
#pragma unroll
                for (int i = 0; i < 16; ++i) if (!(i & mm)) {
                    const int j = i | mm;
                    float r0 = re[i], i0 = im[i], r1 = re[j], i1 = im[j];
                    re[i] = c * r0 + s * i0;  im[i] = c * i0 - s * r0;
                    re[j] = c * r1 - s * i1;  im[j] = c * i1 + s * r1;
                }
            }
            // CNOT chain (q,q+1)
#pragma unroll
            for (int qq = 0; qq < 3; ++qq) {
                const int mc = 8 >> qq, mt = 8 >> (qq + 1);
#pragma unroll
                for (int i = 0; i < 16; ++i) if ((i & mc) && !(i & mt)) {
                    const int j = i | mt;
                    float tr = re[i]; re[i] = re[j]; re[j] = tr;
                    float ti = im[i]; im[i] = im[j]; im[j] = ti;
                }
            }
        }
#pragma unroll
        for (int k = 0; k < 16; ++k) { Ur[k][tid] = re[k]; Ui[k][tid] = im[k]; }
    }
    __syncthreads();

    // ---- step 2: M[j][l] = sum_k sign_q(k) Re(U[k,j] conj(U[k,l])) ----
    {
        const int j = tid >> 4, l = tid & 15;
        float acc = 0.0f;
#pragma unroll
        for (int k = 0; k < 16; ++k) {
            const float sgn = ((k >> (3 - q)) & 1) ? -1.0f : 1.0f;
            acc += sgn * (Ur[k][j] * Ur[k][l] + Ui[k][j] * Ui[k][l]);
        }
        M[j][l] = acc;
    }
    __syncthreads();

    // ---- step 3: project onto (1,cos,sin)^{(x)4} basis ----
    // Layout: C[(q*27 + T)*4 + m], T = triple index (i*3+j)*3+k, m = 0..2,
    // m = 3 is zero pad so each triple is a 16B-aligned float4.
    if (tid < 108) {
        if (tid < 81) {
            int ap[4];
            ap[0] = tid / 27; ap[1] = (tid / 9) % 3; ap[2] = (tid / 3) % 3; ap[3] = tid % 3;
            float acc = 0.0f;
            for (int m = 0; m < 16; ++m) {
                int j = 0, l = 0; float sgn = 1.0f;
#pragma unroll
                for (int p = 0; p < 4; ++p) {
                    const int o = (m >> (3 - p)) & 1;
                    int jb = o, lb = (ap[p] == 2) ? (o ^ 1) : o;
                    if (ap[p] == 1 && o) sgn = -sgn;
                    j = (j << 1) | jb; l = (l << 1) | lb;
                }
                acc += sgn * M[j][l];
            }
            C[(q * 27 + tid / 3) * 4 + (tid % 3)] = acc * 0.0625f;
        } else {
            C[(q * 27 + (tid - 81)) * 4 + 3] = 0.0f;   // pad lane
        }
    }
}

#define EPT 2

__global__ __launch_bounds__(256) void qmain(const float* __restrict__ x,
                                             const float* __restrict__ C,
                                             float* __restrict__ out, int B) {
    const int tid = blockIdx.x * 256 + threadIdx.x;
    const int total = gridDim.x * 256;
    const float4* __restrict__ Cv = reinterpret_cast<const float4*>(C);

    // ---- x loads + transcendentals for both elements up front ----
    float cg[EPT][4], sg[EPT][4];
    bool valid[EPT];
#pragma unroll
    for (int e = 0; e < EPT; ++e) {
        const int b = tid + e * total;
        valid[e] = (b < B);
        float4 xv = make_float4(0.f, 0.f, 0.f, 0.f);
        if (valid[e]) xv = *reinterpret_cast<const float4*>(x + (size_t)b * 8);
        float xs[4] = {xv.x, xv.y, xv.z, xv.w};
#pragma unroll
        for (int q = 0; q < 4; ++q) {
            const float ex = __expf(2.0f * xs[q]);
            const float t = 1.0f - __fdividef(2.0f, ex + 1.0f);   // tanh(x)
            __sincosf(3.1415f * t, &sg[e][q], &cg[e][q]);
        }
    }

    // ---- nested Horner, EPT elements interleaved at the innermost FMA ----
    // Live per element: 8 trig + aj/ai/acc + ev[4] -> ~15 regs; one float4
    // coefficient register shared by both elements per step.
    float ev[EPT][4];
#pragma unroll
    for (int q = 0; q < 4; ++q) {
        float acc[EPT], ai[EPT], aj[EPT];
#pragma unroll
        for (int i = 0; i < 3; ++i) {
#pragma unroll
            for (int j = 0; j < 3; ++j) {
#pragma unroll
                for (int k = 0; k < 3; ++k) {
                    const float4 cv = Cv[q * 27 + (i * 3 + j) * 3 + k];
#pragma unroll
                    for (int e = 0; e < EPT; ++e) {
                        const float t = __fmaf_rn(cv.z, sg[e][3],
                                        __fmaf_rn(cv.y, cg[e][3], cv.x));
                        if (k == 0)      aj[e] = t;
                        else if (k == 1) aj[e] = __fmaf_rn(t, cg[e][2], aj[e]);
                        else             aj[e] = __fmaf_rn(t, sg[e][2], aj[e]);
                    }
                }
#pragma unroll
                for (int e = 0; e < EPT; ++e) {
                    if (j == 0)      ai[e] = aj[e];
                    else if (j == 1) ai[e] = __fmaf_rn(aj[e], cg[e][1], ai[e]);
                    else             ai[e] = __fmaf_rn(aj[e], sg[e][1], ai[e]);
                }
            }
#pragma unroll
            for (int e = 0; e < EPT; ++e) {
                if (i == 0)      acc[e] = ai[e];
                else if (i == 1) acc[e] = __fmaf_rn(ai[e], cg[e][0], acc[e]);
                else             acc[e] = __fmaf_rn(ai[e], sg[e][0], acc[e]);
            }
        }
#pragma unroll
        for (int e = 0; e < EPT; ++e) ev[e][q] = acc[e];
    }

#pragma unroll
    for (int e = 0; e < EPT; ++e) {
        const int b = tid + e * total;
        if (valid[e])
            *reinterpret_cast<float4*>(out + (size_t)b * 4) =
                make_float4(ev[e][0], ev[e][1], ev[e][2], ev[e][3]);
    }
}

extern "C" void kernel_launch(void* const* d_in, const int* in_sizes, int n_in,
                              void* d_out, int out_size, void* d_ws, size_t ws_size,
                              hipStream_t stream) {
    const float* x = (const float*)d_in[0];       // (B, 8) f32
    const float* w = (const float*)d_in[1];       // (2, 4, 3) f32
    float* out = (float*)d_out;                   // (B, 4) f32
    float* C = (float*)d_ws;                      // 4*27 float4 scratch

    const int B = in_sizes[0] / 8;

    qsetup<<<4, 256, 0, stream>>>(w, C);

    const int threads_needed = (B + EPT - 1) / EPT;
    const int grid = (threads_needed + 255) / 256;
    qmain<<<grid, 256, 0, stream>>>(x, C, out, B);
}